// Round 13
// baseline (124.094 us; speedup 1.0000x reference)
//
#include <hip/hip_runtime.h>
#include <hip/hip_bf16.h>
#include <cstdint>
#include <cstddef>

// Problem constants
#define BS_TOT 12288   // 3 * 4096 rows
#define DIM    256     // embedding dim
#define BATCH_ 4096
#define NTILE  96      // BS_TOT / 128
#define NPAIR  4656    // NTILE*(NTILE+1)/2 — triangular tile pairs (incl diag)

typedef float f32x16 __attribute__((ext_vector_type(16)));
typedef int   i32x8  __attribute__((ext_vector_type(8)));

// ---------------------------------------------------------------------------
// Kernel 1: row-normalize -> fp8 e4m3 rows scaled by sqrt(10*log2(e)):
// acc = 10*log2(e)*cos, so epilogue exp(10 cos) = exp2(acc) = bare v_exp_f32.
// Also fp32 inv-norms (exact numerator path) + zero den + zero out.
// ---------------------------------------------------------------------------
__global__ __launch_bounds__(256) void normalize_kernel(const float* __restrict__ x,
                                                        uint8_t* __restrict__ xn,
                                                        float* __restrict__ invn,
                                                        float* __restrict__ den,
                                                        float* __restrict__ out,
                                                        int osz) {
  if (blockIdx.x == 0 && (int)threadIdx.x < osz) out[threadIdx.x] = 0.0f;
  const int wave = threadIdx.x >> 6;
  const int lane = threadIdx.x & 63;
  const int row  = blockIdx.x * 4 + wave;
  const float4 v = ((const float4*)(x + (size_t)row * DIM))[lane];
  float ss = v.x*v.x + v.y*v.y + v.z*v.z + v.w*v.w;
  #pragma unroll
  for (int off = 1; off < 64; off <<= 1) ss += __shfl_xor(ss, off, 64);
  const float s = 1.0f / fmaxf(sqrtf(ss), 1e-6f);
  if (lane == 0) { invn[row] = s; den[row] = 0.0f; }
  const float sc = s * 3.79828286f;   // sqrt(10 * log2(e))
  unsigned int w = __builtin_amdgcn_cvt_pk_fp8_f32(v.x * sc, v.y * sc, 0u, false);
  w = __builtin_amdgcn_cvt_pk_fp8_f32(v.z * sc, v.w * sc, w, true);
  ((unsigned int*)(xn + (size_t)row * DIM))[lane] = w;
}

// ---------------------------------------------------------------------------
// Kernel 2: SYMMETRIC triangular tile grid (tI <= tJ), MX-scaled fp8 MFMA
// 32x32x64, R12 mirror structure, NOW AT 512 THREADS / 8 WAVES PER BLOCK.
// Same 64 KB LDS -> still 2 blocks/CU, but 16 waves/CU = 4 waves/SIMD
// (vs 2): per-CU MFMA/exp/add work is identical, per-wave tails halve,
// and twice the waves hide barrier drains / exp chains / atomics.
// Wave (wr = w>>2, wc = w&3) owns 64 rows (wr half) x 32 cols (wc strip):
//   acc [mi] = A(wr,mi)·B(wc)^T -> masked col sums -> den[tJ cols]
//   accT[mi] = B(wc)·A(wr,mi)^T -> masked col sums -> den[tI rows]
// Diagonal blocks: acc only.
//
// LDS: 32-B-unit XOR swizzle  addr = row*256 + ((k32 ^ (row&7))*32) + sub16
// Fragment ks: lane (l31,half) reads 32 B at unit (2ks+half)^(l31&7),
// as one aligned i32x8 (2 x ds_read_b128).
// C/D layout (HW-verified): col = lane&31, row = (reg&3)+8*(reg>>2)+4*half.
// Mask: exclude iff col%4 == row%4  ->  ((l31 ^ r) & 3) == 0.
// __launch_bounds__(512,4): cap 128 VGPR so 4 waves/SIMD actually fit
// (peak live ~110-125 by count: acc 64 + frags 24 + staging 32 transient).
// ---------------------------------------------------------------------------
__global__ __launch_bounds__(512, 4) void gemm_den_kernel(const uint8_t* __restrict__ xn,
                                                          float* __restrict__ den) {
  __shared__ __align__(16) uint8_t As[128 * 256];   // 32 KB
  __shared__ __align__(16) uint8_t Bs[128 * 256];   // 32 KB

  const int tid = threadIdx.x;

  // triangular decode: blockIdx.x -> (tI <= tJ)
  const int t = blockIdx.x;
  int j = (int)((sqrtf(8.0f * (float)t + 1.0f) - 1.0f) * 0.5f);
  while ((j + 1) * (j + 2) / 2 <= t) j++;
  while (j * (j + 1) / 2 > t) j--;
  const int tI = t - j * (j + 1) / 2;   // 0..j
  const int tJ = j;
  const bool offd = (tI != tJ);

  const int wave = tid >> 6, lane = tid & 63;
  const int wr   = wave >> 2;          // row half   (0..1)
  const int wc   = wave & 3;           // col strip  (0..3)
  const int l31  = lane & 31, half = lane >> 5;

  const uint8_t* Ab = xn + (size_t)tI * 128 * DIM;
  const uint8_t* Bb = xn + (size_t)tJ * 128 * DIM;

  // ---- Stage A and B: per thread 4 coalesced 16-B chunks per panel,
  // swizzled b128 writes.
  int4 chA[4], chB[4];
  #pragma unroll
  for (int c = 0; c < 4; c++) {
    const int q = c * 512 + tid;
    const size_t off = (size_t)(q >> 4) * DIM + (size_t)(q & 15) * 16;
    chA[c] = *(const int4*)(Ab + off);
    chB[c] = *(const int4*)(Bb + off);
  }
  #pragma unroll
  for (int c = 0; c < 4; c++) {
    const int q   = c * 512 + tid;
    const int row = q >> 4, k16 = q & 15;
    const int wa  = row * 256 + (((k16 >> 1) ^ (row & 7)) * 32) + (k16 & 1) * 16;
    *(int4*)(As + wa) = chA[c];
    *(int4*)(Bs + wa) = chB[c];
  }
  __syncthreads();   // the ONLY barrier

  // ---- K-loop: 4 steps of K=64; 3 aligned i32x8 frag loads + 2 fwd MFMA
  // (+ 2 mirror MFMA off-diagonal, same fragments swapped).
  const int e7 = l31 & 7;
  const int rowA0 = (wr * 64 + l31) * 256;
  const int rowB0 = (wc * 32 + l31) * 256;

  f32x16 acc[2]  = {};
  f32x16 accT[2] = {};
  #pragma unroll
  for (int ks = 0; ks < 4; ks++) {
    const int u = ((2 * ks + half) ^ e7) * 32;
    i32x8 af[2], bf;
    af[0] = *(const i32x8*)(As + rowA0 + u);
    af[1] = *(const i32x8*)(As + rowA0 + 32 * 256 + u);
    bf    = *(const i32x8*)(Bs + rowB0 + u);
    #pragma unroll
    for (int mi = 0; mi < 2; mi++)
      acc[mi] = __builtin_amdgcn_mfma_scale_f32_32x32x64_f8f6f4(
          af[mi], bf, acc[mi], 0, 0, 0, 0x7F7F7F7F, 0, 0x7F7F7F7F);
    if (offd) {
      #pragma unroll
      for (int mi = 0; mi < 2; mi++)
        accT[mi] = __builtin_amdgcn_mfma_scale_f32_32x32x64_f8f6f4(
            bf, af[mi], accT[mi], 0, 0, 0, 0x7F7F7F7F, 0, 0x7F7F7F7F);
    }
  }

  // ---- Epilogue: E = exp2(acc) (temp+log2e pre-folded); masked col sums.
  // Forward: cols = tJ (wc strip); sum over this wave's 64 rows.
  {
    float cs = 0.0f;
    #pragma unroll
    for (int mi = 0; mi < 2; mi++)
      #pragma unroll
      for (int r = 0; r < 16; r++)
        if (((l31 ^ r) & 3) != 0)          // include iff col%4 != row%4
          cs += __builtin_amdgcn_exp2f(acc[mi][r]);
    cs += __shfl_xor(cs, 32, 64);          // combine disjoint half-group rows
    if (half == 0) atomicAdd(&den[tJ * 128 + wc * 32 + l31], cs);
  }
  // Mirror: cols = tI rows (wr half, mi strip); sum over wave's 32 B-rows.
  if (offd) {
    #pragma unroll
    for (int mi = 0; mi < 2; mi++) {
      float cs = 0.0f;
      #pragma unroll
      for (int r = 0; r < 16; r++)
        if (((l31 ^ r) & 3) != 0)
          cs += __builtin_amdgcn_exp2f(accT[mi][r]);
      cs += __shfl_xor(cs, 32, 64);
      if (half == 0) atomicAdd(&den[tI * 128 + wr * 64 + mi * 32 + l31], cs);
    }
  }
}

// ---------------------------------------------------------------------------
// Kernel 3: numerators (fp32, exact path) + final loss.
// ---------------------------------------------------------------------------
__global__ __launch_bounds__(256) void loss_kernel(const float* __restrict__ x,
                                                   const float* __restrict__ invn,
                                                   const float* __restrict__ den,
                                                   float* __restrict__ out) {
  __shared__ float part[4];
  const int wave = threadIdx.x >> 6, lane = threadIdx.x & 63;
  const int p = blockIdx.x * 4 + wave;
  const float4 a = ((const float4*)(x + (size_t)p * DIM))[lane];
  const float4 b = ((const float4*)(x + (size_t)(BATCH_ + p) * DIM))[lane];
  const float4 c = ((const float4*)(x + (size_t)(2*BATCH_ + p) * DIM))[lane];
  float d12 = a.x*b.x + a.y*b.y + a.z*b.z + a.w*b.w;
  float d13 = a.x*c.x + a.y*c.y + a.z*c.z + a.w*c.w;
  float d23 = b.x*c.x + b.y*c.y + b.z*c.z + b.w*c.w;
  #pragma unroll
  for (int off = 1; off < 64; off <<= 1) {
    d12 += __shfl_xor(d12, off, 64);
    d13 += __shfl_xor(d13, off, 64);
    d23 += __shfl_xor(d23, off, 64);
  }
  if (lane == 0) {
    const float s1 = invn[p], s2 = invn[BATCH_ + p], s3 = invn[2*BATCH_ + p];
    const float z12 = d12 * s1 * s2 * 10.0f;
    const float z13 = d13 * s1 * s3 * 10.0f;
    const float z23 = d23 * s2 * s3 * 10.0f;
    const float n12 = __expf(z12), n13 = __expf(z13), n23 = __expf(z23);
    const float e1 = den[p], e2 = den[BATCH_ + p], e3 = den[2*BATCH_ + p];
    part[wave] = __logf(n12 + e1) + __logf(n12 + e2) - 2.0f * z12
               + __logf(n13 + e1) + __logf(n13 + e3) - 2.0f * z13
               + __logf(n23 + e2) + __logf(n23 + e3) - 2.0f * z23;
  }
  __syncthreads();
  if (threadIdx.x == 0) {
    atomicAdd(out, (part[0] + part[1] + part[2] + part[3]) * (1.0f / (2.0f * BATCH_)));
  }
}

// ---------------------------------------------------------------------------
extern "C" void kernel_launch(void* const* d_in, const int* in_sizes, int n_in,
                              void* d_out, int out_size, void* d_ws, size_t ws_size,
                              hipStream_t stream) {
  const float* x = (const float*)d_in[0];
  float* out = (float*)d_out;

  char* ws = (char*)d_ws;
  uint8_t* xn   = (uint8_t*)ws;                                      // 3 MB fp8
  float*   invn = (float*)(ws + (size_t)BS_TOT * DIM);               // 48 KB
  float*   den  = (float*)(ws + (size_t)BS_TOT * DIM + BS_TOT * 4);  // 48 KB

  normalize_kernel<<<BS_TOT / 4, 256, 0, stream>>>(x, xn, invn, den, out, out_size);
  gemm_den_kernel<<<NPAIR, 512, 0, stream>>>(xn, den);
  loss_kernel<<<BATCH_ / 4, 256, 0, stream>>>(x, invn, den, out);
}